// Round 3
// baseline (773.901 us; speedup 1.0000x reference)
//
#include <hip/hip_runtime.h>

typedef unsigned short u16;
typedef unsigned int u32;
typedef __attribute__((ext_vector_type(8))) short short8;
typedef __attribute__((ext_vector_type(4))) float f32x4;

#define MFMA16(a, b, c) __builtin_amdgcn_mfma_f32_16x16x32_bf16((a), (b), (c), 0, 0, 0)

__device__ __forceinline__ float b2f(u16 u) {
  union { float f; unsigned int i; } v;
  v.i = ((unsigned int)u) << 16;
  return v.f;
}
__device__ __forceinline__ u16 f2b(float f) {
  union { float f; unsigned int i; } v;
  v.f = f;
  unsigned int x = v.i;
  return (u16)((x + 0x7FFFu + ((x >> 16) & 1u)) >> 16);
}

// ---------------------------------------------------------------------------
// Edge CSR build: count per graph -> scan -> scatter (totals fp32 SoA by head)
// ---------------------------------------------------------------------------
__global__ __launch_bounds__(256) void edge_count_kernel(
    const int* __restrict__ ei, u32* __restrict__ counts, int E) {
  int e = blockIdx.x * 256 + threadIdx.x;
  if (e < E) atomicAdd(&counts[ei[e] >> 7], 1u);
}

__global__ __launch_bounds__(256) void scan_kernel(
    const u32* __restrict__ counts, u32* __restrict__ offsets) {
  __shared__ u32 s[256];
  int t = threadIdx.x;
  s[t] = counts[t];
  __syncthreads();
  for (int d = 1; d < 256; d <<= 1) {
    u32 v = (t >= d) ? s[t - d] : 0u;
    __syncthreads();
    s[t] += v;
    __syncthreads();
  }
  offsets[t + 1] = s[t];
  if (t == 0) offsets[0] = 0;
}

__global__ __launch_bounds__(256) void edge_scatter_kernel(
    const int* __restrict__ ei, const float* __restrict__ ea,
    const int* __restrict__ egt, const float* __restrict__ gate_table,
    const float* __restrict__ We, const float* __restrict__ be,
    const u32* __restrict__ offsets, u32* __restrict__ fill,
    float* __restrict__ etot, u32* __restrict__ epos, int E) {
  int e = blockIdx.x * 256 + threadIdx.x;
  if (e >= E) return;
  int src = ei[e], dst = ei[E + e];
  int g = src >> 7;
  int sl = src & 127, dl = dst & 127;
  int gt = egt[e];
  const float4* eap = (const float4*)(ea + (size_t)e * 8);
  float4 e0 = eap[0], e1 = eap[1];
  float eaf[8] = {e0.x, e0.y, e0.z, e0.w, e1.x, e1.y, e1.z, e1.w};
  u32 pos = offsets[g] + atomicAdd(&fill[g], 1u);
  epos[pos] = (u32)sl | ((u32)dl << 16);
#pragma unroll
  for (int h = 0; h < 8; ++h) {
    float t = gate_table[gt * 8 + h] + be[h];
#pragma unroll
    for (int f = 0; f < 8; ++f) t += eaf[f] * We[f * 8 + h];
    etot[(size_t)h * E + pos] = t;
  }
}

// ---------------------------------------------------------------------------
// GEMM: C[32768,256] = A[32768,256] @ W[256,256](fp32) + bias[256]
// AIN = float (x, fp32) or u16 (bf16 scratch). COUT = u16 (scratch) or float.
// 64x64 tile, BK=32, 4 waves (2x2), mfma_16x16x32_bf16 (fp32 staged -> bf16)
// ---------------------------------------------------------------------------
template <typename AIN, typename COUT>
__global__ __launch_bounds__(256) void gemm_bias_kernel(
    const AIN* __restrict__ A, const float* __restrict__ W,
    const float* __restrict__ bias, COUT* __restrict__ C) {
  constexpr int K = 256, N = 256, LDT = 48;
  __shared__ u16 As[64 * LDT];
  __shared__ u16 Bs[64 * LDT];
  const int tid = threadIdx.x;
  const int bm = blockIdx.x, bn = blockIdx.y;
  const int wid = tid >> 6, lane = tid & 63;
  const int wm = wid >> 1, wn = wid & 1;
  const int quad = lane >> 4, l16 = lane & 15;

  f32x4 acc[2][2] = {};

  const int ar = tid >> 2, ac = (tid & 3) * 8;
  const AIN* aptr = A + (size_t)(bm * 64 + ar) * K + ac;
  const int wk = tid >> 3, wn8 = (tid & 7) * 8;
  const float* wptr = W + (size_t)wk * N + bn * 64 + wn8;

  for (int k0 = 0; k0 < K; k0 += 32) {
    // stage A tile (convert fp32 -> bf16 if needed)
    if constexpr (sizeof(AIN) == 4) {
      const float4* p = (const float4*)(aptr + k0);
      float4 v0 = p[0], v1 = p[1];
      float vf[8] = {v0.x, v0.y, v0.z, v0.w, v1.x, v1.y, v1.z, v1.w};
      short8 s;
#pragma unroll
      for (int j = 0; j < 8; ++j) s[j] = (short)f2b(vf[j]);
      *(short8*)&As[ar * LDT + ac] = s;
    } else {
      *(short8*)&As[ar * LDT + ac] = *(const short8*)(aptr + k0);
    }
    // stage W tile transposed: Bs[n][k]
    {
      const float4* p = (const float4*)(wptr + (size_t)k0 * N);
      float4 v0 = p[0], v1 = p[1];
      float vf[8] = {v0.x, v0.y, v0.z, v0.w, v1.x, v1.y, v1.z, v1.w};
#pragma unroll
      for (int j = 0; j < 8; ++j) Bs[(wn8 + j) * LDT + wk] = f2b(vf[j]);
    }
    __syncthreads();
    short8 a0 = *(short8*)&As[(wm * 32 + l16) * LDT + quad * 8];
    short8 a1 = *(short8*)&As[(wm * 32 + 16 + l16) * LDT + quad * 8];
    short8 b0 = *(short8*)&Bs[(wn * 32 + l16) * LDT + quad * 8];
    short8 b1 = *(short8*)&Bs[(wn * 32 + 16 + l16) * LDT + quad * 8];
    acc[0][0] = MFMA16(a0, b0, acc[0][0]);
    acc[0][1] = MFMA16(a0, b1, acc[0][1]);
    acc[1][0] = MFMA16(a1, b0, acc[1][0]);
    acc[1][1] = MFMA16(a1, b1, acc[1][1]);
    __syncthreads();
  }
#pragma unroll
  for (int j = 0; j < 2; ++j) {
    int col = bn * 64 + wn * 32 + j * 16 + l16;
    float bv = bias[col];
#pragma unroll
    for (int i = 0; i < 2; ++i) {
      int row0 = bm * 64 + wm * 32 + i * 16 + quad * 4;
#pragma unroll
      for (int r = 0; r < 4; ++r) {
        float o = acc[i][j][r] + bv;
        if constexpr (sizeof(COUT) == 4)
          C[(size_t)(row0 + r) * N + col] = o;
        else
          C[(size_t)(row0 + r) * N + col] = f2b(o);
      }
    }
  }
}

// ---------------------------------------------------------------------------
// Fused attention per (q-half, head, graph). S = scale*Q@K^T in LDS fp32,
// edge bias applied via LDS atomics from per-graph CSR, unnormalized softmax
// (1/Z deferred), P@V via MFMA. LDS: Pb aliases dead Qs/Ks (61.7 KB total).
// ---------------------------------------------------------------------------
__global__ __launch_bounds__(256) void attn_kernel(
    const u16* __restrict__ Q, const u16* __restrict__ K,
    const u16* __restrict__ V, const u32* __restrict__ offsets,
    const u32* __restrict__ epos, const float* __restrict__ etot,
    u16* __restrict__ O, int E) {
  constexpr int LQK = 48, LV = 144, LP = 136, LS = 132;
  __shared__ __align__(16) char smem[61696];
  float* S   = (float*)smem;                    // 33792 B
  u16*   Qs  = (u16*)(smem + 33792);            //  6144 B
  u16*   Ks  = (u16*)(smem + 39936);            // 12288 B
  u16*   Pb  = (u16*)(smem + 33792);            // 17408 B (aliases Qs+Ks)
  u16*   Vt  = (u16*)(smem + 52224);            //  9216 B
  float* inv = (float*)(smem + 61440);          //   256 B

  const int tid = threadIdx.x;
  const int qh = blockIdx.x, h = blockIdx.y, b = blockIdx.z;
  const int q0 = qh * 64;
  const int wid = tid >> 6, lane = tid & 63;
  const int quad = lane >> 4, l16 = lane & 15;

  // Load Q tile (64 rows x 32)
  {
    int r = tid >> 2, s = (tid & 3) * 8;
    const u16* p = Q + (size_t)(b * 128 + q0 + r) * 256 + h * 32 + s;
    *(short8*)&Qs[r * LQK + s] = *(const short8*)p;
  }
  // Load K tile (128 rows x 32)
  {
    int r = tid >> 1, s = (tid & 1) * 16;
    const u16* p = K + (size_t)(b * 128 + r) * 256 + h * 32 + s;
    *(short8*)&Ks[r * LQK + s] = *(const short8*)p;
    *(short8*)&Ks[r * LQK + s + 8] = *(const short8*)(p + 8);
  }
  // Load V transposed: Vt[d][k_node]
  {
    int r = tid >> 1, s = (tid & 1) * 16;
    const u16* p = V + (size_t)(b * 128 + r) * 256 + h * 32 + s;
    short8 v0 = *(const short8*)p;
    short8 v1 = *(const short8*)(p + 8);
#pragma unroll
    for (int j = 0; j < 8; ++j) {
      Vt[(s + j) * LV + r] = (u16)v0[j];
      Vt[(s + 8 + j) * LV + r] = (u16)v1[j];
    }
  }
  __syncthreads();

  // S = scale * Q @ K^T  (each wave: 16 q-rows x 128 k-cols) -> LDS fp32
  const float scale = 0.17677669529663687f;
  {
    short8 aq = *(short8*)&Qs[(wid * 16 + l16) * LQK + quad * 8];
#pragma unroll
    for (int j = 0; j < 8; ++j) {
      short8 bk = *(short8*)&Ks[(j * 16 + l16) * LQK + quad * 8];
      f32x4 z = {0.f, 0.f, 0.f, 0.f};
      f32x4 sv = MFMA16(aq, bk, z);
#pragma unroll
      for (int r = 0; r < 4; ++r)
        S[(wid * 16 + quad * 4 + r) * LS + j * 16 + l16] = sv[r] * scale;
    }
  }
  __syncthreads();

  // Apply edge bias from this graph's CSR slice via LDS atomics
  {
    int e0 = offsets[b], e1 = offsets[b + 1];
    const float* et = etot + (size_t)h * E;
    for (int e = e0 + tid; e < e1; e += 256) {
      u32 pd = epos[e];
      int sl = pd & 0xffff, dl = pd >> 16;
      float t = et[e];
      int sr = sl - q0, dr = dl - q0;
      if ((unsigned)sr < 64u) atomicAdd(&S[sr * LS + dl], t);
      if (sl != dl && (unsigned)dr < 64u) atomicAdd(&S[dr * LS + sl], t);
    }
  }
  __syncthreads();

  // Unnormalized softmax: 4 threads per row, 32 cols each; writes Pb (bf16)
  {
    int row = tid >> 2, c0 = (tid & 3) * 32;
    const float* srow = &S[row * LS + c0];
    float m = -1e30f;
#pragma unroll
    for (int c = 0; c < 32; ++c) m = fmaxf(m, srow[c]);
    m = fmaxf(m, __shfl_xor(m, 1, 64));
    m = fmaxf(m, __shfl_xor(m, 2, 64));
    float sum = 0.f;
    u16 prow[32];
#pragma unroll
    for (int c = 0; c < 32; ++c) {
      float p = __expf(srow[c] - m);
      sum += p;
      prow[c] = f2b(p);
    }
    sum += __shfl_xor(sum, 1, 64);
    sum += __shfl_xor(sum, 2, 64);
    __syncthreads();  // S fully read; Pb may now overwrite Qs/Ks region
#pragma unroll
    for (int c = 0; c < 32; ++c) Pb[row * LP + c0 + c] = prow[c];
    if ((tid & 3) == 0) inv[row] = 1.f / sum;
  }
  __syncthreads();

  // O = (P @ V) * inv
  f32x4 oacc[2] = {};
#pragma unroll
  for (int ks = 0; ks < 4; ++ks) {
    short8 ap = *(short8*)&Pb[(wid * 16 + l16) * LP + ks * 32 + quad * 8];
#pragma unroll
    for (int j = 0; j < 2; ++j) {
      short8 bv = *(short8*)&Vt[(j * 16 + l16) * LV + ks * 32 + quad * 8];
      oacc[j] = MFMA16(ap, bv, oacc[j]);
    }
  }
#pragma unroll
  for (int j = 0; j < 2; ++j)
#pragma unroll
    for (int r = 0; r < 4; ++r) {
      int qr = wid * 16 + quad * 4 + r;
      float iv = inv[qr];
      O[(size_t)(b * 128 + q0 + qr) * 256 + h * 32 + j * 16 + l16] =
          f2b(oacc[j][r] * iv);
    }
}

// ---------------------------------------------------------------------------

extern "C" void kernel_launch(void* const* d_in, const int* in_sizes, int n_in,
                              void* d_out, int out_size, void* d_ws, size_t ws_size,
                              hipStream_t stream) {
  const float* x    = (const float*)d_in[0];
  const float* ea   = (const float*)d_in[1];
  const float* Wq   = (const float*)d_in[2];
  const float* bq   = (const float*)d_in[3];
  const float* Wk   = (const float*)d_in[4];
  const float* bk   = (const float*)d_in[5];
  const float* Wv   = (const float*)d_in[6];
  const float* bv   = (const float*)d_in[7];
  const float* Wo   = (const float*)d_in[8];
  const float* bo   = (const float*)d_in[9];
  const float* gate = (const float*)d_in[10];
  const float* We   = (const float*)d_in[11];
  const float* be   = (const float*)d_in[12];
  const int*   ei   = (const int*)d_in[13];
  const int*   egt  = (const int*)d_in[14];
  const int    E    = in_sizes[14];

  const size_t matBytes = (size_t)32768 * 256 * 2;  // 16.78 MB per bf16 matrix

  char* ws = (char*)d_ws;
  u16* Qm = (u16*)ws;
  u16* Km = (u16*)(ws + matBytes);
  u16* Vm = (u16*)(ws + 2 * matBytes);
  u16* Om = (u16*)(ws + 3 * matBytes);
  float* etot  = (float*)(ws + 4 * matBytes);                    // 8*E fp32
  u32*   epos  = (u32*)(ws + 4 * matBytes + (size_t)8 * E * 4);  // E u32
  u32*   counts = (u32*)(ws + 4 * matBytes + (size_t)9 * E * 4);
  u32*   fill   = counts + 256;
  u32*   offsets = counts + 512;  // 257 entries

  hipMemsetAsync(counts, 0, (512 + 257) * sizeof(u32), stream);

  int eb = (E + 255) / 256;
  edge_count_kernel<<<dim3(eb), dim3(256), 0, stream>>>(ei, counts, E);
  scan_kernel<<<dim3(1), dim3(256), 0, stream>>>(counts, offsets);
  edge_scatter_kernel<<<dim3(eb), dim3(256), 0, stream>>>(
      ei, ea, egt, gate, We, be, offsets, fill, etot, epos, E);

  dim3 gg(512, 4);
  gemm_bias_kernel<float, u16><<<gg, dim3(256), 0, stream>>>(x, Wq, bq, Qm);
  gemm_bias_kernel<float, u16><<<gg, dim3(256), 0, stream>>>(x, Wk, bk, Km);
  gemm_bias_kernel<float, u16><<<gg, dim3(256), 0, stream>>>(x, Wv, bv, Vm);

  attn_kernel<<<dim3(2, 8, 256), dim3(256), 0, stream>>>(
      Qm, Km, Vm, offsets, epos, etot, Om, E);

  gemm_bias_kernel<u16, float><<<gg, dim3(256), 0, stream>>>(
      Om, Wo, bo, (float*)d_out);
}

// Round 4
// 547.388 us; speedup vs baseline: 1.4138x; 1.4138x over previous
//
#include <hip/hip_runtime.h>

typedef unsigned short u16;
typedef unsigned int u32;
typedef __attribute__((ext_vector_type(8))) short short8;
typedef __attribute__((ext_vector_type(4))) float f32x4;

#define MFMA16(a, b, c) __builtin_amdgcn_mfma_f32_16x16x32_bf16((a), (b), (c), 0, 0, 0)

__device__ __forceinline__ float b2f(u16 u) {
  union { float f; unsigned int i; } v;
  v.i = ((unsigned int)u) << 16;
  return v.f;
}
__device__ __forceinline__ u16 f2b(float f) {
  union { float f; unsigned int i; } v;
  v.f = f;
  unsigned int x = v.i;
  return (u16)((x + 0x7FFFu + ((x >> 16) & 1u)) >> 16);
}

// ---------------------------------------------------------------------------
// x (fp32) -> bf16, 8 elems/thread
// ---------------------------------------------------------------------------
__global__ __launch_bounds__(256) void cvt_kernel(
    const float* __restrict__ x, u16* __restrict__ xb) {
  size_t i = ((size_t)blockIdx.x * 256 + threadIdx.x) * 8;
  const float4* p = (const float4*)(x + i);
  float4 v0 = p[0], v1 = p[1];
  float vf[8] = {v0.x, v0.y, v0.z, v0.w, v1.x, v1.y, v1.z, v1.w};
  short8 s;
#pragma unroll
  for (int j = 0; j < 8; ++j) s[j] = (short)f2b(vf[j]);
  *(short8*)(xb + i) = s;
}

// ---------------------------------------------------------------------------
// Edge CSR build: LDS-histogram count -> scan -> scatter (AoS records)
// ---------------------------------------------------------------------------
__global__ __launch_bounds__(256) void edge_count_kernel(
    const int* __restrict__ ei, u32* __restrict__ counts, int E) {
  __shared__ u32 hist[256];
  hist[threadIdx.x] = 0;
  __syncthreads();
  for (int e = blockIdx.x * 256 + threadIdx.x; e < E; e += gridDim.x * 256)
    atomicAdd(&hist[ei[e] >> 7], 1u);
  __syncthreads();
  u32 v = hist[threadIdx.x];
  if (v) atomicAdd(&counts[threadIdx.x], v);
}

__global__ __launch_bounds__(256) void scan_kernel(
    const u32* __restrict__ counts, u32* __restrict__ offsets) {
  __shared__ u32 s[256];
  int t = threadIdx.x;
  s[t] = counts[t];
  __syncthreads();
  for (int d = 1; d < 256; d <<= 1) {
    u32 v = (t >= d) ? s[t - d] : 0u;
    __syncthreads();
    s[t] += v;
    __syncthreads();
  }
  offsets[t + 1] = s[t];
  if (t == 0) offsets[0] = 0;
}

__global__ __launch_bounds__(256) void edge_scatter_kernel(
    const int* __restrict__ ei, const float* __restrict__ ea,
    const int* __restrict__ egt, const float* __restrict__ gate_table,
    const float* __restrict__ We, const float* __restrict__ be,
    const u32* __restrict__ offsets, u32* __restrict__ fill,
    float* __restrict__ etot, u32* __restrict__ epos, int E) {
  int e = blockIdx.x * 256 + threadIdx.x;
  if (e >= E) return;
  int src = ei[e], dst = ei[E + e];
  int g = src >> 7;
  int sl = src & 127, dl = dst & 127;
  int gt = egt[e];
  const float4* eap = (const float4*)(ea + (size_t)e * 8);
  float4 e0 = eap[0], e1 = eap[1];
  float eaf[8] = {e0.x, e0.y, e0.z, e0.w, e1.x, e1.y, e1.z, e1.w};
  float t[8];
#pragma unroll
  for (int h = 0; h < 8; ++h) {
    float s = gate_table[gt * 8 + h] + be[h];
#pragma unroll
    for (int f = 0; f < 8; ++f) s += eaf[f] * We[f * 8 + h];
    t[h] = s;
  }
  u32 pos = offsets[g] + atomicAdd(&fill[g], 1u);
  epos[pos] = (u32)sl | ((u32)dl << 16);
  float4* outp = (float4*)(etot + (size_t)pos * 8);
  outp[0] = make_float4(t[0], t[1], t[2], t[3]);
  outp[1] = make_float4(t[4], t[5], t[6], t[7]);
}

// ---------------------------------------------------------------------------
// GEMM: C[32768,256] = A[32768,256](bf16) @ W[256,256](fp32) + bias[256]
// 64x64 tile, BK=32, 4 waves (2x2), mfma_16x16x32_bf16
// ---------------------------------------------------------------------------
template <typename COUT>
__global__ __launch_bounds__(256) void gemm_bias_kernel(
    const u16* __restrict__ A, const float* __restrict__ W,
    const float* __restrict__ bias, COUT* __restrict__ C) {
  constexpr int K = 256, N = 256, LDT = 48;
  __shared__ u16 As[64 * LDT];
  __shared__ u16 Bs[64 * LDT];
  const int tid = threadIdx.x;
  const int bm = blockIdx.x, bn = blockIdx.y;
  const int wid = tid >> 6, lane = tid & 63;
  const int wm = wid >> 1, wn = wid & 1;
  const int quad = lane >> 4, l16 = lane & 15;

  f32x4 acc[2][2] = {};

  const int ar = tid >> 2, ac = (tid & 3) * 8;
  const u16* aptr = A + (size_t)(bm * 64 + ar) * K + ac;
  const int wk = tid >> 3, wn8 = (tid & 7) * 8;
  const float* wptr = W + (size_t)wk * N + bn * 64 + wn8;

  for (int k0 = 0; k0 < K; k0 += 32) {
    *(short8*)&As[ar * LDT + ac] = *(const short8*)(aptr + k0);
    // stage W tile transposed: Bs[n][k], fp32 -> bf16
    {
      const float4* p = (const float4*)(wptr + (size_t)k0 * N);
      float4 v0 = p[0], v1 = p[1];
      float vf[8] = {v0.x, v0.y, v0.z, v0.w, v1.x, v1.y, v1.z, v1.w};
#pragma unroll
      for (int j = 0; j < 8; ++j) Bs[(wn8 + j) * LDT + wk] = f2b(vf[j]);
    }
    __syncthreads();
    short8 a0 = *(short8*)&As[(wm * 32 + l16) * LDT + quad * 8];
    short8 a1 = *(short8*)&As[(wm * 32 + 16 + l16) * LDT + quad * 8];
    short8 b0 = *(short8*)&Bs[(wn * 32 + l16) * LDT + quad * 8];
    short8 b1 = *(short8*)&Bs[(wn * 32 + 16 + l16) * LDT + quad * 8];
    acc[0][0] = MFMA16(a0, b0, acc[0][0]);
    acc[0][1] = MFMA16(a0, b1, acc[0][1]);
    acc[1][0] = MFMA16(a1, b0, acc[1][0]);
    acc[1][1] = MFMA16(a1, b1, acc[1][1]);
    __syncthreads();
  }
#pragma unroll
  for (int j = 0; j < 2; ++j) {
    int col = bn * 64 + wn * 32 + j * 16 + l16;
    float bv = bias[col];
#pragma unroll
    for (int i = 0; i < 2; ++i) {
      int row0 = bm * 64 + wm * 32 + i * 16 + quad * 4;
#pragma unroll
      for (int r = 0; r < 4; ++r) {
        float o = acc[i][j][r] + bv;
        if constexpr (sizeof(COUT) == 4)
          C[(size_t)(row0 + r) * N + col] = o;
        else
          C[(size_t)(row0 + r) * N + col] = f2b(o);
      }
    }
  }
}

// ---------------------------------------------------------------------------
// Fused attention per (q-half, head, graph). S = scale*Q@K^T in LDS fp32,
// edge bias applied via LDS atomics from per-graph CSR, unnormalized softmax
// (1/Z deferred), P@V via MFMA. LDS: Pb aliases dead Qs/Ks (61.7 KB total).
// ---------------------------------------------------------------------------
__global__ __launch_bounds__(256) void attn_kernel(
    const u16* __restrict__ Q, const u16* __restrict__ K,
    const u16* __restrict__ V, const u32* __restrict__ offsets,
    const u32* __restrict__ epos, const float* __restrict__ etot,
    u16* __restrict__ O, int E) {
  constexpr int LQK = 48, LV = 144, LP = 136, LS = 132;
  __shared__ __align__(16) char smem[61696];
  float* S   = (float*)smem;                    // 33792 B
  u16*   Qs  = (u16*)(smem + 33792);            //  6144 B
  u16*   Ks  = (u16*)(smem + 39936);            // 12288 B
  u16*   Pb  = (u16*)(smem + 33792);            // 17408 B (aliases Qs+Ks)
  u16*   Vt  = (u16*)(smem + 52224);            //  9216 B
  float* inv = (float*)(smem + 61440);          //   256 B

  const int tid = threadIdx.x;
  const int qh = blockIdx.x, h = blockIdx.y, b = blockIdx.z;
  const int q0 = qh * 64;
  const int wid = tid >> 6, lane = tid & 63;
  const int quad = lane >> 4, l16 = lane & 15;

  // Load Q tile (64 rows x 32)
  {
    int r = tid >> 2, s = (tid & 3) * 8;
    const u16* p = Q + (size_t)(b * 128 + q0 + r) * 256 + h * 32 + s;
    *(short8*)&Qs[r * LQK + s] = *(const short8*)p;
  }
  // Load K tile (128 rows x 32)
  {
    int r = tid >> 1, s = (tid & 1) * 16;
    const u16* p = K + (size_t)(b * 128 + r) * 256 + h * 32 + s;
    *(short8*)&Ks[r * LQK + s] = *(const short8*)p;
    *(short8*)&Ks[r * LQK + s + 8] = *(const short8*)(p + 8);
  }
  // Load V transposed: Vt[d][k_node]
  {
    int r = tid >> 1, s = (tid & 1) * 16;
    const u16* p = V + (size_t)(b * 128 + r) * 256 + h * 32 + s;
    short8 v0 = *(const short8*)p;
    short8 v1 = *(const short8*)(p + 8);
#pragma unroll
    for (int j = 0; j < 8; ++j) {
      Vt[(s + j) * LV + r] = (u16)v0[j];
      Vt[(s + 8 + j) * LV + r] = (u16)v1[j];
    }
  }
  __syncthreads();

  // S = scale * Q @ K^T  (each wave: 16 q-rows x 128 k-cols) -> LDS fp32
  const float scale = 0.17677669529663687f;
  {
    short8 aq = *(short8*)&Qs[(wid * 16 + l16) * LQK + quad * 8];
#pragma unroll
    for (int j = 0; j < 8; ++j) {
      short8 bk = *(short8*)&Ks[(j * 16 + l16) * LQK + quad * 8];
      f32x4 z = {0.f, 0.f, 0.f, 0.f};
      f32x4 sv = MFMA16(aq, bk, z);
#pragma unroll
      for (int r = 0; r < 4; ++r)
        S[(wid * 16 + quad * 4 + r) * LS + j * 16 + l16] = sv[r] * scale;
    }
  }
  __syncthreads();

  // Apply edge bias from this graph's CSR slice via LDS atomics
  {
    int e0 = offsets[b], e1 = offsets[b + 1];
    for (int e = e0 + tid; e < e1; e += 256) {
      u32 pd = epos[e];
      int sl = pd & 0xffff, dl = pd >> 16;
      float t = etot[(size_t)e * 8 + h];
      int sr = sl - q0, dr = dl - q0;
      if ((unsigned)sr < 64u) atomicAdd(&S[sr * LS + dl], t);
      if (sl != dl && (unsigned)dr < 64u) atomicAdd(&S[dr * LS + sl], t);
    }
  }
  __syncthreads();

  // Unnormalized softmax: 4 threads per row, 32 cols each; writes Pb (bf16)
  {
    int row = tid >> 2, c0 = (tid & 3) * 32;
    const float* srow = &S[row * LS + c0];
    float m = -1e30f;
#pragma unroll
    for (int c = 0; c < 32; ++c) m = fmaxf(m, srow[c]);
    m = fmaxf(m, __shfl_xor(m, 1, 64));
    m = fmaxf(m, __shfl_xor(m, 2, 64));
    float sum = 0.f;
    u16 prow[32];
#pragma unroll
    for (int c = 0; c < 32; ++c) {
      float p = __expf(srow[c] - m);
      sum += p;
      prow[c] = f2b(p);
    }
    sum += __shfl_xor(sum, 1, 64);
    sum += __shfl_xor(sum, 2, 64);
    __syncthreads();  // S fully read; Pb may now overwrite Qs/Ks region
#pragma unroll
    for (int c = 0; c < 32; ++c) Pb[row * LP + c0 + c] = prow[c];
    if ((tid & 3) == 0) inv[row] = 1.f / sum;
  }
  __syncthreads();

  // O = (P @ V) * inv
  f32x4 oacc[2] = {};
#pragma unroll
  for (int ks = 0; ks < 4; ++ks) {
    short8 ap = *(short8*)&Pb[(wid * 16 + l16) * LP + ks * 32 + quad * 8];
#pragma unroll
    for (int j = 0; j < 2; ++j) {
      short8 bv = *(short8*)&Vt[(j * 16 + l16) * LV + ks * 32 + quad * 8];
      oacc[j] = MFMA16(ap, bv, oacc[j]);
    }
  }
#pragma unroll
  for (int j = 0; j < 2; ++j)
#pragma unroll
    for (int r = 0; r < 4; ++r) {
      int qr = wid * 16 + quad * 4 + r;
      float iv = inv[qr];
      O[(size_t)(b * 128 + q0 + qr) * 256 + h * 32 + j * 16 + l16] =
          f2b(oacc[j][r] * iv);
    }
}

// ---------------------------------------------------------------------------

extern "C" void kernel_launch(void* const* d_in, const int* in_sizes, int n_in,
                              void* d_out, int out_size, void* d_ws, size_t ws_size,
                              hipStream_t stream) {
  const float* x    = (const float*)d_in[0];
  const float* ea   = (const float*)d_in[1];
  const float* Wq   = (const float*)d_in[2];
  const float* bq   = (const float*)d_in[3];
  const float* Wk   = (const float*)d_in[4];
  const float* bk   = (const float*)d_in[5];
  const float* Wv   = (const float*)d_in[6];
  const float* bv   = (const float*)d_in[7];
  const float* Wo   = (const float*)d_in[8];
  const float* bo   = (const float*)d_in[9];
  const float* gate = (const float*)d_in[10];
  const float* We   = (const float*)d_in[11];
  const float* be   = (const float*)d_in[12];
  const int*   ei   = (const int*)d_in[13];
  const int*   egt  = (const int*)d_in[14];
  const int    E    = in_sizes[14];

  const size_t matBytes = (size_t)32768 * 256 * 2;  // 16.78 MB per bf16 matrix

  char* ws = (char*)d_ws;
  u16* Qm = (u16*)ws;
  u16* Km = (u16*)(ws + matBytes);
  u16* Vm = (u16*)(ws + 2 * matBytes);
  u16* Om = (u16*)(ws + 3 * matBytes);
  u16* xb = Om;  // xb aliases Om: xb dead before attn writes Om
  float* etot  = (float*)(ws + 4 * matBytes);                    // E*8 fp32 AoS
  u32*   epos  = (u32*)(ws + 4 * matBytes + (size_t)8 * E * 4);  // E u32
  u32*   counts = (u32*)(ws + 4 * matBytes + (size_t)9 * E * 4);
  u32*   fill   = counts + 256;
  u32*   offsets = counts + 512;  // 257 entries

  hipMemsetAsync(counts, 0, (512 + 257) * sizeof(u32), stream);

  int eb = (E + 255) / 256;
  edge_count_kernel<<<dim3(256), dim3(256), 0, stream>>>(ei, counts, E);
  scan_kernel<<<dim3(1), dim3(256), 0, stream>>>(counts, offsets);
  edge_scatter_kernel<<<dim3(eb), dim3(256), 0, stream>>>(
      ei, ea, egt, gate, We, be, offsets, fill, etot, epos, E);

  cvt_kernel<<<dim3(4096), dim3(256), 0, stream>>>(x, xb);

  dim3 gg(512, 4);
  gemm_bias_kernel<u16><<<gg, dim3(256), 0, stream>>>(xb, Wq, bq, Qm);
  gemm_bias_kernel<u16><<<gg, dim3(256), 0, stream>>>(xb, Wk, bk, Km);
  gemm_bias_kernel<u16><<<gg, dim3(256), 0, stream>>>(xb, Wv, bv, Vm);

  attn_kernel<<<dim3(2, 8, 256), dim3(256), 0, stream>>>(
      Qm, Km, Vm, offsets, epos, etot, Om, E);

  gemm_bias_kernel<float><<<gg, dim3(256), 0, stream>>>(
      Om, Wo, bo, (float*)d_out);
}

// Round 5
// 329.923 us; speedup vs baseline: 2.3457x; 1.6591x over previous
//
#include <hip/hip_runtime.h>

typedef unsigned short u16;
typedef unsigned int u32;
typedef __attribute__((ext_vector_type(8))) short short8;
typedef __attribute__((ext_vector_type(4))) float f32x4;

#define MFMA16(a, b, c) __builtin_amdgcn_mfma_f32_16x16x32_bf16((a), (b), (c), 0, 0, 0)

__device__ __forceinline__ float b2f(u16 u) {
  union { float f; unsigned int i; } v;
  v.i = ((unsigned int)u) << 16;
  return v.f;
}
__device__ __forceinline__ u16 f2b(float f) {
  union { float f; unsigned int i; } v;
  v.f = f;
  unsigned int x = v.i;
  return (u16)((x + 0x7FFFu + ((x >> 16) & 1u)) >> 16);
}

// ---------------------------------------------------------------------------
// x (fp32) -> bf16, 8 elems/thread
// ---------------------------------------------------------------------------
__global__ __launch_bounds__(256) void cvt_kernel(
    const float* __restrict__ x, u16* __restrict__ xb) {
  size_t i = ((size_t)blockIdx.x * 256 + threadIdx.x) * 8;
  const float4* p = (const float4*)(x + i);
  float4 v0 = p[0], v1 = p[1];
  float vf[8] = {v0.x, v0.y, v0.z, v0.w, v1.x, v1.y, v1.z, v1.w};
  short8 s;
#pragma unroll
  for (int j = 0; j < 8; ++j) s[j] = (short)f2b(vf[j]);
  *(short8*)(xb + i) = s;
}

// ---------------------------------------------------------------------------
// Edge CSR build: LDS-histogram count -> scan -> block-aggregated scatter
// ---------------------------------------------------------------------------
__global__ __launch_bounds__(256) void edge_count_kernel(
    const int* __restrict__ ei, u32* __restrict__ counts, int E) {
  __shared__ u32 hist[256];
  hist[threadIdx.x] = 0;
  __syncthreads();
  for (int e = blockIdx.x * 256 + threadIdx.x; e < E; e += gridDim.x * 256)
    atomicAdd(&hist[ei[e] >> 7], 1u);
  __syncthreads();
  u32 v = hist[threadIdx.x];
  if (v) atomicAdd(&counts[threadIdx.x], v);
}

__global__ __launch_bounds__(256) void scan_kernel(
    const u32* __restrict__ counts, u32* __restrict__ offsets) {
  __shared__ u32 s[256];
  int t = threadIdx.x;
  s[t] = counts[t];
  __syncthreads();
  for (int d = 1; d < 256; d <<= 1) {
    u32 v = (t >= d) ? s[t - d] : 0u;
    __syncthreads();
    s[t] += v;
    __syncthreads();
  }
  offsets[t + 1] = s[t];
  if (t == 0) offsets[0] = 0;
}

// Each block owns 2048 consecutive edges. Phase 1: LDS histogram of graph
// ids. Phase 2: one global atomic per non-empty bin onto 64B-padded gfill
// (kills same-line atomic serialization). Phase 3: scatter via LDS cursors.
__global__ __launch_bounds__(256) void edge_build_kernel(
    const int* __restrict__ ei, const float* __restrict__ ea,
    const int* __restrict__ egt, const float* __restrict__ gate_table,
    const float* __restrict__ We, const float* __restrict__ be,
    const u32* __restrict__ offsets, u32* __restrict__ gfill,
    float* __restrict__ etot, u32* __restrict__ epos, int E) {
  __shared__ u32 hist[256];
  __shared__ u32 cursor[256];
  const int tid = threadIdx.x;
  hist[tid] = 0;
  __syncthreads();
  const int base_e = blockIdx.x * 2048;
  int gcache[8];
#pragma unroll
  for (int i = 0; i < 8; ++i) {
    int e = base_e + i * 256 + tid;
    int g = (e < E) ? (ei[e] >> 7) : -1;
    gcache[i] = g;
    if (g >= 0) atomicAdd(&hist[(u32)g], 1u);
  }
  __syncthreads();
  {
    u32 c = hist[tid];
    u32 r = c ? atomicAdd(&gfill[tid * 16], c) : 0u;
    cursor[tid] = offsets[tid] + r;
  }
  __syncthreads();
#pragma unroll
  for (int i = 0; i < 8; ++i) {
    int g = gcache[i];
    if (g < 0) continue;
    int e = base_e + i * 256 + tid;
    int src = ei[e], dst = ei[E + e];
    int sl = src & 127, dl = dst & 127;
    int gt = egt[e];
    const float4* eap = (const float4*)(ea + (size_t)e * 8);
    float4 e0 = eap[0], e1 = eap[1];
    float eaf[8] = {e0.x, e0.y, e0.z, e0.w, e1.x, e1.y, e1.z, e1.w};
    float t[8];
#pragma unroll
    for (int h = 0; h < 8; ++h) {
      float s = gate_table[gt * 8 + h] + be[h];
#pragma unroll
      for (int f = 0; f < 8; ++f) s += eaf[f] * We[f * 8 + h];
      t[h] = s;
    }
    u32 pos = atomicAdd(&cursor[(u32)g], 1u);
    epos[pos] = (u32)sl | ((u32)dl << 16);
    float4* outp = (float4*)(etot + (size_t)pos * 8);
    outp[0] = make_float4(t[0], t[1], t[2], t[3]);
    outp[1] = make_float4(t[4], t[5], t[6], t[7]);
  }
}

// ---------------------------------------------------------------------------
// GEMM: C[32768,256] = A[32768,256](bf16) @ W[256,256](fp32) + bias[256]
// 64x64 tile, BK=32, 4 waves (2x2), mfma_16x16x32_bf16
// ---------------------------------------------------------------------------
template <typename COUT>
__global__ __launch_bounds__(256) void gemm_bias_kernel(
    const u16* __restrict__ A, const float* __restrict__ W,
    const float* __restrict__ bias, COUT* __restrict__ C) {
  constexpr int K = 256, N = 256, LDT = 48;
  __shared__ u16 As[64 * LDT];
  __shared__ u16 Bs[64 * LDT];
  const int tid = threadIdx.x;
  const int bm = blockIdx.x, bn = blockIdx.y;
  const int wid = tid >> 6, lane = tid & 63;
  const int wm = wid >> 1, wn = wid & 1;
  const int quad = lane >> 4, l16 = lane & 15;

  f32x4 acc[2][2] = {};

  const int ar = tid >> 2, ac = (tid & 3) * 8;
  const u16* aptr = A + (size_t)(bm * 64 + ar) * K + ac;
  const int wk = tid >> 3, wn8 = (tid & 7) * 8;
  const float* wptr = W + (size_t)wk * N + bn * 64 + wn8;

  for (int k0 = 0; k0 < K; k0 += 32) {
    *(short8*)&As[ar * LDT + ac] = *(const short8*)(aptr + k0);
    {
      const float4* p = (const float4*)(wptr + (size_t)k0 * N);
      float4 v0 = p[0], v1 = p[1];
      float vf[8] = {v0.x, v0.y, v0.z, v0.w, v1.x, v1.y, v1.z, v1.w};
#pragma unroll
      for (int j = 0; j < 8; ++j) Bs[(wn8 + j) * LDT + wk] = f2b(vf[j]);
    }
    __syncthreads();
    short8 a0 = *(short8*)&As[(wm * 32 + l16) * LDT + quad * 8];
    short8 a1 = *(short8*)&As[(wm * 32 + 16 + l16) * LDT + quad * 8];
    short8 b0 = *(short8*)&Bs[(wn * 32 + l16) * LDT + quad * 8];
    short8 b1 = *(short8*)&Bs[(wn * 32 + 16 + l16) * LDT + quad * 8];
    acc[0][0] = MFMA16(a0, b0, acc[0][0]);
    acc[0][1] = MFMA16(a0, b1, acc[0][1]);
    acc[1][0] = MFMA16(a1, b0, acc[1][0]);
    acc[1][1] = MFMA16(a1, b1, acc[1][1]);
    __syncthreads();
  }
#pragma unroll
  for (int j = 0; j < 2; ++j) {
    int col = bn * 64 + wn * 32 + j * 16 + l16;
    float bv = bias[col];
#pragma unroll
    for (int i = 0; i < 2; ++i) {
      int row0 = bm * 64 + wm * 32 + i * 16 + quad * 4;
#pragma unroll
      for (int r = 0; r < 4; ++r) {
        float o = acc[i][j][r] + bv;
        if constexpr (sizeof(COUT) == 4)
          C[(size_t)(row0 + r) * N + col] = o;
        else
          C[(size_t)(row0 + r) * N + col] = f2b(o);
      }
    }
  }
}

// ---------------------------------------------------------------------------
// Fused attention per (q-half, head, graph). S = scale*Q@K^T in LDS fp32,
// edge bias applied via LDS atomics from per-graph CSR, unnormalized softmax
// (1/Z deferred), P@V via MFMA. LDS: Pb aliases dead Qs/Ks (61.7 KB total).
// ---------------------------------------------------------------------------
__global__ __launch_bounds__(256) void attn_kernel(
    const u16* __restrict__ Q, const u16* __restrict__ K,
    const u16* __restrict__ V, const u32* __restrict__ offsets,
    const u32* __restrict__ epos, const float* __restrict__ etot,
    u16* __restrict__ O, int E) {
  constexpr int LQK = 48, LV = 144, LP = 136, LS = 132;
  __shared__ __align__(16) char smem[61696];
  float* S   = (float*)smem;                    // 33792 B
  u16*   Qs  = (u16*)(smem + 33792);            //  6144 B
  u16*   Ks  = (u16*)(smem + 39936);            // 12288 B
  u16*   Pb  = (u16*)(smem + 33792);            // 17408 B (aliases Qs+Ks)
  u16*   Vt  = (u16*)(smem + 52224);            //  9216 B
  float* inv = (float*)(smem + 61440);          //   256 B

  const int tid = threadIdx.x;
  const int qh = blockIdx.x, h = blockIdx.y, b = blockIdx.z;
  const int q0 = qh * 64;
  const int wid = tid >> 6, lane = tid & 63;
  const int quad = lane >> 4, l16 = lane & 15;

  {
    int r = tid >> 2, s = (tid & 3) * 8;
    const u16* p = Q + (size_t)(b * 128 + q0 + r) * 256 + h * 32 + s;
    *(short8*)&Qs[r * LQK + s] = *(const short8*)p;
  }
  {
    int r = tid >> 1, s = (tid & 1) * 16;
    const u16* p = K + (size_t)(b * 128 + r) * 256 + h * 32 + s;
    *(short8*)&Ks[r * LQK + s] = *(const short8*)p;
    *(short8*)&Ks[r * LQK + s + 8] = *(const short8*)(p + 8);
  }
  {
    int r = tid >> 1, s = (tid & 1) * 16;
    const u16* p = V + (size_t)(b * 128 + r) * 256 + h * 32 + s;
    short8 v0 = *(const short8*)p;
    short8 v1 = *(const short8*)(p + 8);
#pragma unroll
    for (int j = 0; j < 8; ++j) {
      Vt[(s + j) * LV + r] = (u16)v0[j];
      Vt[(s + 8 + j) * LV + r] = (u16)v1[j];
    }
  }
  __syncthreads();

  const float scale = 0.17677669529663687f;
  {
    short8 aq = *(short8*)&Qs[(wid * 16 + l16) * LQK + quad * 8];
#pragma unroll
    for (int j = 0; j < 8; ++j) {
      short8 bk = *(short8*)&Ks[(j * 16 + l16) * LQK + quad * 8];
      f32x4 z = {0.f, 0.f, 0.f, 0.f};
      f32x4 sv = MFMA16(aq, bk, z);
#pragma unroll
      for (int r = 0; r < 4; ++r)
        S[(wid * 16 + quad * 4 + r) * LS + j * 16 + l16] = sv[r] * scale;
    }
  }
  __syncthreads();

  {
    int e0 = offsets[b], e1 = offsets[b + 1];
    for (int e = e0 + tid; e < e1; e += 256) {
      u32 pd = epos[e];
      int sl = pd & 0xffff, dl = pd >> 16;
      float t = etot[(size_t)e * 8 + h];
      int sr = sl - q0, dr = dl - q0;
      if ((unsigned)sr < 64u) atomicAdd(&S[sr * LS + dl], t);
      if (sl != dl && (unsigned)dr < 64u) atomicAdd(&S[dr * LS + sl], t);
    }
  }
  __syncthreads();

  {
    int row = tid >> 2, c0 = (tid & 3) * 32;
    const float* srow = &S[row * LS + c0];
    float m = -1e30f;
#pragma unroll
    for (int c = 0; c < 32; ++c) m = fmaxf(m, srow[c]);
    m = fmaxf(m, __shfl_xor(m, 1, 64));
    m = fmaxf(m, __shfl_xor(m, 2, 64));
    float sum = 0.f;
    u16 prow[32];
#pragma unroll
    for (int c = 0; c < 32; ++c) {
      float p = __expf(srow[c] - m);
      sum += p;
      prow[c] = f2b(p);
    }
    sum += __shfl_xor(sum, 1, 64);
    sum += __shfl_xor(sum, 2, 64);
    __syncthreads();
#pragma unroll
    for (int c = 0; c < 32; ++c) Pb[row * LP + c0 + c] = prow[c];
    if ((tid & 3) == 0) inv[row] = 1.f / sum;
  }
  __syncthreads();

  f32x4 oacc[2] = {};
#pragma unroll
  for (int ks = 0; ks < 4; ++ks) {
    short8 ap = *(short8*)&Pb[(wid * 16 + l16) * LP + ks * 32 + quad * 8];
#pragma unroll
    for (int j = 0; j < 2; ++j) {
      short8 bv = *(short8*)&Vt[(j * 16 + l16) * LV + ks * 32 + quad * 8];
      oacc[j] = MFMA16(ap, bv, oacc[j]);
    }
  }
#pragma unroll
  for (int j = 0; j < 2; ++j)
#pragma unroll
    for (int r = 0; r < 4; ++r) {
      int qr = wid * 16 + quad * 4 + r;
      float iv = inv[qr];
      O[(size_t)(b * 128 + q0 + qr) * 256 + h * 32 + j * 16 + l16] =
          f2b(oacc[j][r] * iv);
    }
}

// ---------------------------------------------------------------------------

extern "C" void kernel_launch(void* const* d_in, const int* in_sizes, int n_in,
                              void* d_out, int out_size, void* d_ws, size_t ws_size,
                              hipStream_t stream) {
  const float* x    = (const float*)d_in[0];
  const float* ea   = (const float*)d_in[1];
  const float* Wq   = (const float*)d_in[2];
  const float* bq   = (const float*)d_in[3];
  const float* Wk   = (const float*)d_in[4];
  const float* bk   = (const float*)d_in[5];
  const float* Wv   = (const float*)d_in[6];
  const float* bv   = (const float*)d_in[7];
  const float* Wo   = (const float*)d_in[8];
  const float* bo   = (const float*)d_in[9];
  const float* gate = (const float*)d_in[10];
  const float* We   = (const float*)d_in[11];
  const float* be   = (const float*)d_in[12];
  const int*   ei   = (const int*)d_in[13];
  const int*   egt  = (const int*)d_in[14];
  const int    E    = in_sizes[14];

  const size_t matBytes = (size_t)32768 * 256 * 2;  // 16.78 MB per bf16 matrix

  char* ws = (char*)d_ws;
  u16* Qm = (u16*)ws;
  u16* Km = (u16*)(ws + matBytes);
  u16* Vm = (u16*)(ws + 2 * matBytes);
  u16* Om = (u16*)(ws + 3 * matBytes);
  u16* xb = Om;  // xb aliases Om: xb dead before attn writes Om
  float* etot  = (float*)(ws + 4 * matBytes);                    // E*8 fp32 AoS
  u32*   epos  = (u32*)(ws + 4 * matBytes + (size_t)8 * E * 4);  // E u32
  u32*   counts = (u32*)(ws + 4 * matBytes + (size_t)9 * E * 4);
  u32*   offsets = counts + 256;   // 257 entries
  u32*   gfill   = counts + 768;   // 256 counters padded to 64 B apart (4096 u32)

  // zero counts + (offsets, harmless) + gfill
  hipMemsetAsync(counts, 0, (768 + 4096) * sizeof(u32), stream);

  edge_count_kernel<<<dim3(256), dim3(256), 0, stream>>>(ei, counts, E);
  scan_kernel<<<dim3(1), dim3(256), 0, stream>>>(counts, offsets);
  edge_build_kernel<<<dim3((E + 2047) / 2048), dim3(256), 0, stream>>>(
      ei, ea, egt, gate, We, be, offsets, gfill, etot, epos, E);

  cvt_kernel<<<dim3(4096), dim3(256), 0, stream>>>(x, xb);

  dim3 gg(512, 4);
  gemm_bias_kernel<u16><<<gg, dim3(256), 0, stream>>>(xb, Wq, bq, Qm);
  gemm_bias_kernel<u16><<<gg, dim3(256), 0, stream>>>(xb, Wk, bk, Km);
  gemm_bias_kernel<u16><<<gg, dim3(256), 0, stream>>>(xb, Wv, bv, Vm);

  attn_kernel<<<dim3(2, 8, 256), dim3(256), 0, stream>>>(
      Qm, Km, Vm, offsets, epos, etot, Om, E);

  gemm_bias_kernel<float><<<gg, dim3(256), 0, stream>>>(
      Om, Wo, bo, (float*)d_out);
}